// Round 1
// baseline (113.964 us; speedup 1.0000x reference)
//
#include <hip/hip_runtime.h>

// RAVENlog: out = shift*ln2 - Horner4_quantized(0.75 - x*2^-shift)
// shift = floor(log2(x)) + 1 (exact via exponent bits; x in [0.25, 8) is normal)
//
// Quantize(v, iw=7, fw): round-half-even(v*2^fw)/2^fw clamped to [-128, 128-2^-fw].
// All scale muls are powers of two (exact); rintf == jnp.round (half-to-even).
// __f*_rn intrinsics prevent FMA contraction so arithmetic matches the
// reference's separate mul/add rounding bit-exactly.

__device__ __forceinline__ float qstep(float acc, float var, float c,
                                       float s, float invs, float hi) {
    float t = __fadd_rn(__fmul_rn(acc, var), c);   // no FMA: match jnp rounding
    float q = __fmul_rn(rintf(__fmul_rn(t, s)), invs);  // exact scale, rne round
    return fminf(fmaxf(q, -128.0f), hi);
}

__device__ __forceinline__ float raven_elem(float x) {
    unsigned int b = __float_as_uint(x);
    // shift = ((exp_field - 127) ) + 1 = exp_field - 126
    float shiftf = (float)((int)((b >> 23) & 0xFFu) - 126);
    // m = x * 2^-shift in [0.5, 1): replace exponent with 126
    float m = __uint_as_float((b & 0x007FFFFFu) | 0x3F000000u);
    float var = __fsub_rn(0.75f, m);   // exact (both on 2^-24 grid, |diff|<=0.25)

    // coeff = float32 of [-log(0.75), 1/0.75, 1/(2*0.75^2), 1/(3*0.75^3)]
    const float c0 = 0.2876820724517809f;
    const float c1 = 1.3333333333333333f;
    const float c2 = 0.8888888888888888f;
    const float c3 = 0.7901234567901234f;

    // fracwidth = [8,7,6,5], evaluated idx=3..0
    float acc = qstep(0.0f, var, c3,  32.0f, 0.03125f,    128.0f - 0.03125f);
    acc       = qstep(acc,  var, c2,  64.0f, 0.015625f,   128.0f - 0.015625f);
    acc       = qstep(acc,  var, c1, 128.0f, 0.0078125f,  128.0f - 0.0078125f);
    acc       = qstep(acc,  var, c0, 256.0f, 0.00390625f, 128.0f - 0.00390625f);

    const float LN2F = 0.6931471805599453f;
    return __fsub_rn(__fmul_rn(shiftf, LN2F), acc);
}

__global__ void __launch_bounds__(256)
raven_kernel(const float* __restrict__ x, float* __restrict__ out, int n4) {
    int stride = gridDim.x * blockDim.x;
    for (int i = blockIdx.x * blockDim.x + threadIdx.x; i < n4; i += stride) {
        float4 v = reinterpret_cast<const float4*>(x)[i];
        float4 r;
        r.x = raven_elem(v.x);
        r.y = raven_elem(v.y);
        r.z = raven_elem(v.z);
        r.w = raven_elem(v.w);
        reinterpret_cast<float4*>(out)[i] = r;
    }
}

extern "C" void kernel_launch(void* const* d_in, const int* in_sizes, int n_in,
                              void* d_out, int out_size, void* d_ws, size_t ws_size,
                              hipStream_t stream) {
    const float* x = (const float*)d_in[0];
    float* out = (float*)d_out;
    int n = in_sizes[0];          // 67,108,864 (divisible by 4)
    int n4 = n >> 2;
    const int block = 256;
    const int grid = 2048;        // grid-stride; ~32 float4 iters/thread
    raven_kernel<<<grid, block, 0, stream>>>(x, out, n4);
}

// Round 3
// 99.264 us; speedup vs baseline: 1.1481x; 1.1481x over previous
//
#include <hip/hip_runtime.h>

// RAVENlog: out = shift*ln2 - Horner4_quantized(0.75 - x*2^-shift)
// shift = floor(log2(x)) + 1 (exact via exponent bits; x in [0.25, 8) is normal)
//
// Quantize(v, iw=7, fw): round-half-even(v*2^fw)/2^fw clamped to [-128, 128-2^-fw].
// All scale muls are powers of two (exact); rintf == jnp.round (half-to-even).
// __f*_rn intrinsics prevent FMA contraction so arithmetic matches the
// reference's separate mul/add rounding bit-exactly.
//
// R3: nontemporal via clang ext_vector_type (HIP float4 is a class, rejected
// by the builtin); 2-stream manual unroll for more loads in flight.

typedef float v4f __attribute__((ext_vector_type(4)));

__device__ __forceinline__ float qstep(float acc, float var, float c,
                                       float s, float invs, float hi) {
    float t = __fadd_rn(__fmul_rn(acc, var), c);   // no FMA: match jnp rounding
    float q = __fmul_rn(rintf(__fmul_rn(t, s)), invs);  // exact scale, rne round
    return fminf(fmaxf(q, -128.0f), hi);
}

__device__ __forceinline__ float raven_elem(float x) {
    unsigned int b = __float_as_uint(x);
    float shiftf = (float)((int)((b >> 23) & 0xFFu) - 126);
    float m = __uint_as_float((b & 0x007FFFFFu) | 0x3F000000u);
    float var = __fsub_rn(0.75f, m);   // exact

    const float c0 = 0.2876820724517809f;
    const float c1 = 1.3333333333333333f;
    const float c2 = 0.8888888888888888f;
    const float c3 = 0.7901234567901234f;

    float acc = qstep(0.0f, var, c3,  32.0f, 0.03125f,    128.0f - 0.03125f);
    acc       = qstep(acc,  var, c2,  64.0f, 0.015625f,   128.0f - 0.015625f);
    acc       = qstep(acc,  var, c1, 128.0f, 0.0078125f,  128.0f - 0.0078125f);
    acc       = qstep(acc,  var, c0, 256.0f, 0.00390625f, 128.0f - 0.00390625f);

    const float LN2F = 0.6931471805599453f;
    return __fsub_rn(__fmul_rn(shiftf, LN2F), acc);
}

__device__ __forceinline__ v4f raven4(v4f v) {
    v4f r;
    r.x = raven_elem(v.x);
    r.y = raven_elem(v.y);
    r.z = raven_elem(v.z);
    r.w = raven_elem(v.w);
    return r;
}

__global__ void __launch_bounds__(256)
raven_kernel(const v4f* __restrict__ x, v4f* __restrict__ out, int half4) {
    // two coalesced streams: [0, half4) and [half4, 2*half4)
    int stride = gridDim.x * blockDim.x;
    for (int i = blockIdx.x * blockDim.x + threadIdx.x; i < half4; i += stride) {
        v4f a = __builtin_nontemporal_load(x + i);
        v4f b = __builtin_nontemporal_load(x + i + half4);
        v4f ra = raven4(a);
        v4f rb = raven4(b);
        __builtin_nontemporal_store(ra, out + i);
        __builtin_nontemporal_store(rb, out + i + half4);
    }
}

extern "C" void kernel_launch(void* const* d_in, const int* in_sizes, int n_in,
                              void* d_out, int out_size, void* d_ws, size_t ws_size,
                              hipStream_t stream) {
    const float* x = (const float*)d_in[0];
    float* out = (float*)d_out;
    int n = in_sizes[0];          // 67,108,864 (divisible by 8)
    int half4 = n >> 3;           // float4 count per half-stream
    const int block = 256;
    const int grid = 2048;        // 8 blocks/CU, 32 waves/CU
    raven_kernel<<<grid, block, 0, stream>>>(
        reinterpret_cast<const v4f*>(x), reinterpret_cast<v4f*>(out), half4);
}